// Round 1
// baseline (1004.704 us; speedup 1.0000x reference)
//
#include <hip/hip_runtime.h>
#include <math.h>

#define BB 32
#define NN 1024
#define DD 128

// ---------------- K1: t[b*N+j] = dot(P[b,j,:], wa) ----------------
__global__ void k_bias(const float* __restrict__ P, const float* __restrict__ w_itr,
                       float* __restrict__ t) {
    int tid = threadIdx.x;
    int lane4 = tid & 3;                       // 4 lanes per row
    long row = (long)blockIdx.x * 64 + (tid >> 2);
    const float4* p4 = (const float4*)(P + row * DD);
    const float4* wa4 = (const float4*)w_itr;  // wa = w_itr_att[0:128]
    float s = 0.f;
#pragma unroll
    for (int i = 0; i < 8; ++i) {
        int c4 = lane4 * 8 + i;
        float4 a = p4[c4];
        float4 b = wa4[c4];
        s += a.x * b.x + a.y * b.y + a.z * b.z + a.w * b.w;
    }
    s += __shfl_xor(s, 1);
    s += __shfl_xor(s, 2);
    if (lane4 == 0) t[row] = s;
}

// ---------------- K2: flash-style attention ----------------
// logits[i,j] = t[j] + (P_i * wc) . P_j ; SA = softmax_j ; attn_i = sum_j SA * P_j
// Block: 256 threads = 32 groups of 8 lanes; each group owns RPG=4 query rows.
// d-dimension (128) sliced across the 8 lanes: lane sub owns d = 4*sub+32*dd (+0..3).
#define QT 128
#define KT 32
#define RPG 4
#define KST 132  // padded LDS row stride (floats)

__global__ __launch_bounds__(256, 1) void k_attn(const float* __restrict__ P,
                                                 const float* __restrict__ w_itr,
                                                 const float* __restrict__ t,
                                                 float* __restrict__ attn) {
    __shared__ float Ks[KT][KST];
    __shared__ float tt[KT];
    int tid = threadIdx.x;
    int sub = tid & 7;
    int g = tid >> 3;                 // 0..31
    int b = blockIdx.x >> 3;          // grid = 32 * 8
    int qt = blockIdx.x & 7;
    int i0 = qt * QT + g * RPG;
    const float* Pb = P + (long)b * NN * DD;
    const float4* wc4 = (const float4*)(w_itr + 2 * DD);

    // q fragments: 4 rows x 16 d-components (registers)
    float4 qf[RPG][4];
#pragma unroll
    for (int r = 0; r < RPG; ++r) {
        const float4* src = (const float4*)(Pb + (long)(i0 + r) * DD);
#pragma unroll
        for (int dd = 0; dd < 4; ++dd) {
            int c4 = sub + 8 * dd;
            float4 v = src[c4];
            float4 w = wc4[c4];
            v.x *= w.x; v.y *= w.y; v.z *= w.z; v.w *= w.w;
            qf[r][dd] = v;
        }
    }
    float4 o[RPG][4];
    float m_run[RPG], l_run[RPG];
#pragma unroll
    for (int r = 0; r < RPG; ++r) {
        m_run[r] = -INFINITY; l_run[r] = 0.f;
#pragma unroll
        for (int dd = 0; dd < 4; ++dd) o[r][dd] = make_float4(0.f, 0.f, 0.f, 0.f);
    }
    const float* tb = t + (long)b * NN;

    for (int jt = 0; jt < NN / KT; ++jt) {
        __syncthreads();
        {   // stage K tile (32 x 128 fp32), coalesced float4
            const float4* src = (const float4*)(Pb + (long)jt * KT * DD);
#pragma unroll
            for (int i = 0; i < (KT * DD / 4) / 256; ++i) {
                int idx = tid + i * 256;
                int row = idx >> 5, c4 = idx & 31;
                *((float4*)&Ks[row][c4 * 4]) = src[idx];
            }
            if (tid < KT) tt[tid] = tb[jt * KT + tid];
        }
        __syncthreads();

        // ---- phase A: logits (each lane keeps logits for j = sub + 8*jj) ----
        float lg[RPG][KT / 8];
#pragma unroll
        for (int r = 0; r < RPG; ++r)
#pragma unroll
            for (int jj = 0; jj < KT / 8; ++jj) lg[r][jj] = 0.f;

#pragma unroll
        for (int jj = 0; jj < KT / 8; ++jj) {
#pragma unroll 2
            for (int jin = 0; jin < 8; ++jin) {
                int j = jj * 8 + jin;
                float4 kv0 = *(const float4*)&Ks[j][4 * sub];
                float4 kv1 = *(const float4*)&Ks[j][4 * (sub + 8)];
                float4 kv2 = *(const float4*)&Ks[j][4 * (sub + 16)];
                float4 kv3 = *(const float4*)&Ks[j][4 * (sub + 24)];
#pragma unroll
                for (int r = 0; r < RPG; ++r) {
                    float s =
                        qf[r][0].x * kv0.x + qf[r][0].y * kv0.y + qf[r][0].z * kv0.z + qf[r][0].w * kv0.w +
                        qf[r][1].x * kv1.x + qf[r][1].y * kv1.y + qf[r][1].z * kv1.z + qf[r][1].w * kv1.w +
                        qf[r][2].x * kv2.x + qf[r][2].y * kv2.y + qf[r][2].z * kv2.z + qf[r][2].w * kv2.w +
                        qf[r][3].x * kv3.x + qf[r][3].y * kv3.y + qf[r][3].z * kv3.z + qf[r][3].w * kv3.w;
                    s += __shfl_xor(s, 1);
                    s += __shfl_xor(s, 2);
                    s += __shfl_xor(s, 4);
                    lg[r][jj] = (jin == sub) ? (s + tt[j]) : lg[r][jj];
                }
            }
        }

        // ---- phase B: online softmax update ----
        float p[RPG][KT / 8];
#pragma unroll
        for (int r = 0; r < RPG; ++r) {
            float mx = fmaxf(fmaxf(lg[r][0], lg[r][1]), fmaxf(lg[r][2], lg[r][3]));
            mx = fmaxf(mx, __shfl_xor(mx, 1));
            mx = fmaxf(mx, __shfl_xor(mx, 2));
            mx = fmaxf(mx, __shfl_xor(mx, 4));
            float nm = fmaxf(m_run[r], mx);
            float alpha = __expf(m_run[r] - nm);
            float ts = 0.f;
#pragma unroll
            for (int jj = 0; jj < KT / 8; ++jj) {
                p[r][jj] = __expf(lg[r][jj] - nm);
                ts += p[r][jj];
            }
            ts += __shfl_xor(ts, 1);
            ts += __shfl_xor(ts, 2);
            ts += __shfl_xor(ts, 4);
            l_run[r] = l_run[r] * alpha + ts;
            m_run[r] = nm;
#pragma unroll
            for (int dd = 0; dd < 4; ++dd) {
                o[r][dd].x *= alpha; o[r][dd].y *= alpha;
                o[r][dd].z *= alpha; o[r][dd].w *= alpha;
            }
        }

        // ---- phase C: accumulate o += p_j * K_j (lane's d-slice) ----
#pragma unroll
        for (int jj = 0; jj < KT / 8; ++jj) {
#pragma unroll 2
            for (int jin = 0; jin < 8; ++jin) {
                int j = jj * 8 + jin;
                float4 kv0 = *(const float4*)&Ks[j][4 * sub];
                float4 kv1 = *(const float4*)&Ks[j][4 * (sub + 8)];
                float4 kv2 = *(const float4*)&Ks[j][4 * (sub + 16)];
                float4 kv3 = *(const float4*)&Ks[j][4 * (sub + 24)];
                int srcl = (tid & 56) | jin;
#pragma unroll
                for (int r = 0; r < RPG; ++r) {
                    float pj = __shfl(p[r][jj], srcl);
                    o[r][0].x += pj * kv0.x; o[r][0].y += pj * kv0.y; o[r][0].z += pj * kv0.z; o[r][0].w += pj * kv0.w;
                    o[r][1].x += pj * kv1.x; o[r][1].y += pj * kv1.y; o[r][1].z += pj * kv1.z; o[r][1].w += pj * kv1.w;
                    o[r][2].x += pj * kv2.x; o[r][2].y += pj * kv2.y; o[r][2].z += pj * kv2.z; o[r][2].w += pj * kv2.w;
                    o[r][3].x += pj * kv3.x; o[r][3].y += pj * kv3.y; o[r][3].z += pj * kv3.z; o[r][3].w += pj * kv3.w;
                }
            }
        }
    }

    // epilogue: normalize and write itr_attn
    float* ab = attn + ((long)b * NN + i0) * DD;
#pragma unroll
    for (int r = 0; r < RPG; ++r) {
        float inv = 1.f / l_run[r];
#pragma unroll
        for (int dd = 0; dd < 4; ++dd) {
            float4 v = o[r][dd];
            v.x *= inv; v.y *= inv; v.z *= inv; v.w *= inv;
            *((float4*)&ab[r * DD + 4 * (sub + 8 * dd)]) = v;
        }
    }
}

// ---------------- K3: gated MLP ----------------
// out = sigmoid(C@w2+b2) * P + sigmoid(C@w3+b3) * tanh(C@w1+b1), C = [P, attn]
__device__ inline void fma4(float4& a, float c, const float4 w) {
    a.x += c * w.x; a.y += c * w.y; a.z += c * w.z; a.w += c * w.w;
}
__device__ inline float sigm(float x) { return 1.f / (1.f + __expf(-x)); }

__global__ __launch_bounds__(256) void k_mlp(const float* __restrict__ P,
                                             const float* __restrict__ attn,
                                             const float* __restrict__ w1,
                                             const float* __restrict__ w2,
                                             const float* __restrict__ w3,
                                             const float* __restrict__ b1,
                                             const float* __restrict__ b2,
                                             const float* __restrict__ b3,
                                             float* __restrict__ out) {
    __shared__ float wsh[3][32][128];
    int tid = threadIdx.x;
    int tx = tid & 15;                 // cols tx*8 .. tx*8+7
    int ty = tid >> 4;                 // rows ty*4 .. ty*4+3
    long row0 = (long)blockIdx.x * 64 + ty * 4;

    float4 a1[4][2], a2[4][2], a3[4][2];
#pragma unroll
    for (int i = 0; i < 4; ++i)
#pragma unroll
        for (int h = 0; h < 2; ++h) {
            a1[i][h] = make_float4(0.f, 0.f, 0.f, 0.f);
            a2[i][h] = make_float4(0.f, 0.f, 0.f, 0.f);
            a3[i][h] = make_float4(0.f, 0.f, 0.f, 0.f);
        }

    for (int kt = 0; kt < 8; ++kt) {
        __syncthreads();
        {
            const float* wptr0 = w1; const float* wptr1 = w2; const float* wptr2 = w3;
#pragma unroll
            for (int i = 0; i < 12; ++i) {
                int f4idx = tid + i * 256;            // 0..3071
                int mat = f4idx >> 10;                // constant per unrolled i
                int rem = f4idx & 1023;
                int kr = rem >> 5, c4 = rem & 31;
                const float* wp = (mat == 0) ? wptr0 : ((mat == 1) ? wptr1 : wptr2);
                *((float4*)&wsh[mat][kr][c4 * 4]) =
                    *((const float4*)&wp[(kt * 32 + kr) * 128 + c4 * 4]);
            }
        }
        __syncthreads();
        const float* Csrc = (kt < 4) ? P : attn;
        int kbase = (kt * 32) & 127;
        for (int k = 0; k < 32; ++k) {
            float cv[4];
#pragma unroll
            for (int i = 0; i < 4; ++i)
                cv[i] = Csrc[(row0 + i) * DD + kbase + k];
            float4 wv10 = *((const float4*)&wsh[0][k][tx * 8]);
            float4 wv11 = *((const float4*)&wsh[0][k][tx * 8 + 4]);
            float4 wv20 = *((const float4*)&wsh[1][k][tx * 8]);
            float4 wv21 = *((const float4*)&wsh[1][k][tx * 8 + 4]);
            float4 wv30 = *((const float4*)&wsh[2][k][tx * 8]);
            float4 wv31 = *((const float4*)&wsh[2][k][tx * 8 + 4]);
#pragma unroll
            for (int i = 0; i < 4; ++i) {
                float c = cv[i];
                fma4(a1[i][0], c, wv10); fma4(a1[i][1], c, wv11);
                fma4(a2[i][0], c, wv20); fma4(a2[i][1], c, wv21);
                fma4(a3[i][0], c, wv30); fma4(a3[i][1], c, wv31);
            }
        }
    }

    float4 b1v[2], b2v[2], b3v[2];
#pragma unroll
    for (int h = 0; h < 2; ++h) {
        b1v[h] = ((const float4*)b1)[tx * 2 + h];
        b2v[h] = ((const float4*)b2)[tx * 2 + h];
        b3v[h] = ((const float4*)b3)[tx * 2 + h];
    }
#pragma unroll
    for (int i = 0; i < 4; ++i) {
        const float4* Prow = (const float4*)(P + (row0 + i) * DD);
        float4* Orow = (float4*)(out + (row0 + i) * DD);
#pragma unroll
        for (int h = 0; h < 2; ++h) {
            float4 pv = Prow[tx * 2 + h];
            float4 res;
            float z, rr, ff;
            z = tanhf(a1[i][h].x + b1v[h].x); rr = sigm(a2[i][h].x + b2v[h].x); ff = sigm(a3[i][h].x + b3v[h].x);
            res.x = rr * pv.x + ff * z;
            z = tanhf(a1[i][h].y + b1v[h].y); rr = sigm(a2[i][h].y + b2v[h].y); ff = sigm(a3[i][h].y + b3v[h].y);
            res.y = rr * pv.y + ff * z;
            z = tanhf(a1[i][h].z + b1v[h].z); rr = sigm(a2[i][h].z + b2v[h].z); ff = sigm(a3[i][h].z + b3v[h].z);
            res.z = rr * pv.z + ff * z;
            z = tanhf(a1[i][h].w + b1v[h].w); rr = sigm(a2[i][h].w + b2v[h].w); ff = sigm(a3[i][h].w + b3v[h].w);
            res.w = rr * pv.w + ff * z;
            Orow[tx * 2 + h] = res;
        }
    }
}

extern "C" void kernel_launch(void* const* d_in, const int* in_sizes, int n_in,
                              void* d_out, int out_size, void* d_ws, size_t ws_size,
                              hipStream_t stream) {
    const float* P     = (const float*)d_in[0];
    const float* w_itr = (const float*)d_in[1];
    const float* w1    = (const float*)d_in[2];
    const float* w2    = (const float*)d_in[3];
    const float* w3    = (const float*)d_in[4];
    const float* b1    = (const float*)d_in[5];
    const float* b2    = (const float*)d_in[6];
    const float* b3    = (const float*)d_in[7];
    float* out = (float*)d_out;

    float* t_ws    = (float*)d_ws;                   // B*N floats
    float* attn_ws = t_ws + (long)BB * NN;           // B*N*D floats

    k_bias<<<dim3((BB * NN) / 64), dim3(256), 0, stream>>>(P, w_itr, t_ws);
    k_attn<<<dim3(BB * (NN / QT)), dim3(256), 0, stream>>>(P, w_itr, t_ws, attn_ws);
    k_mlp<<<dim3((BB * NN) / 64), dim3(256), 0, stream>>>(P, attn_ws, w1, w2, w3, b1, b2, b3, out);
}

// Round 2
// 190.447 us; speedup vs baseline: 5.2755x; 5.2755x over previous
//
#include <hip/hip_runtime.h>
#include <math.h>

#define BB 32
#define NN 1024
#define DD 128

typedef __bf16 bf16;
typedef bf16 bf16x4 __attribute__((ext_vector_type(4)));
typedef bf16 bf16x8 __attribute__((ext_vector_type(8)));
typedef float f32x4 __attribute__((ext_vector_type(4)));

#define MFMA(a, b, c) __builtin_amdgcn_mfma_f32_16x16x32_bf16(a, b, c, 0, 0, 0)

__device__ inline bf16x8 cvt8(const float4 a, const float4 b) {
    bf16x8 r;
    r[0] = (bf16)a.x; r[1] = (bf16)a.y; r[2] = (bf16)a.z; r[3] = (bf16)a.w;
    r[4] = (bf16)b.x; r[5] = (bf16)b.y; r[6] = (bf16)b.z; r[7] = (bf16)b.w;
    return r;
}

// ---------------- K0: prep ----------------
// Produces: Xbf[32768][256] cols 0..127 = bf16(P); Pq = bf16(P*wc);
// Ptp[b][d][n'] = bf16(P[b][n][d]) with per-64 key permutation n' = 4*ln+kt;
// t[b][n] = P_n . wa   (wb is dead: constant over softmax axis)
__global__ __launch_bounds__(256) void k_prep(const float* __restrict__ P,
                                              const float* __restrict__ w_itr,
                                              bf16* __restrict__ Xbf,
                                              bf16* __restrict__ Pq,
                                              bf16* __restrict__ Ptp,
                                              float* __restrict__ t) {
    __shared__ bf16 Lt[128 * 72];  // transposed+permuted tile [d][row']
    int tid = threadIdx.x;
    int b = blockIdx.x >> 4, g = blockIdx.x & 15;
    int n0 = g * 64;
    int row = tid >> 2, q = tid & 3, d0 = q * 32;
    long brow = (long)b * NN + n0 + row;

    const float* src = P + brow * DD + d0;
    float r[32];
#pragma unroll
    for (int i = 0; i < 8; ++i) {
        float4 v = ((const float4*)src)[i];
        r[4 * i + 0] = v.x; r[4 * i + 1] = v.y; r[4 * i + 2] = v.z; r[4 * i + 3] = v.w;
    }
    // t = P . wa  (wa = w_itr[0:128])
    float s = 0.f;
#pragma unroll
    for (int k = 0; k < 32; ++k) s += r[k] * w_itr[d0 + k];
    s += __shfl_xor(s, 1);
    s += __shfl_xor(s, 2);
    if (q == 0) t[brow] = s;
    // Xbf (P as bf16) and Pq (P*wc as bf16)
    const float* wc = w_itr + 2 * DD;
#pragma unroll
    for (int i = 0; i < 4; ++i) {
        bf16x8 xv, qv;
#pragma unroll
        for (int e = 0; e < 8; ++e) {
            float f = r[8 * i + e];
            xv[e] = (bf16)f;
            qv[e] = (bf16)(f * wc[d0 + 8 * i + e]);
        }
        *(bf16x8*)&Xbf[brow * 256 + d0 + 8 * i] = xv;
        *(bf16x8*)&Pq[brow * DD + d0 + 8 * i] = qv;
    }
    // transposed permuted tile: row' = 4*(row&15) + (row>>4)
    int rowp = ((row & 15) << 2) | ((row >> 4) & 3);
#pragma unroll
    for (int k = 0; k < 32; ++k) Lt[(d0 + k) * 72 + rowp] = (bf16)r[k];
    __syncthreads();
#pragma unroll
    for (int i = 0; i < 4; ++i) {
        int idx = tid + i * 256;           // 0..1023
        int d = idx >> 3, c = idx & 7;
        *(float4*)&Ptp[((long)b * DD + d) * NN + n0 + c * 8] =
            *(const float4*)&Lt[d * 72 + c * 8];
    }
}

// ---------------- K0b: weight transpose ----------------
// WtG[mat][col][k] = bf16(w_mat[k][col]);  mat-major, col stride 256
__global__ __launch_bounds__(256) void k_prepw(const float* __restrict__ w1,
                                               const float* __restrict__ w2,
                                               const float* __restrict__ w3,
                                               bf16* __restrict__ WtG) {
    int idx = blockIdx.x * 256 + threadIdx.x;   // 0 .. 98303
    int mat = idx >> 15, rem = idx & 32767;
    int col = rem >> 8, k = rem & 255;
    const float* w = (mat == 0) ? w1 : ((mat == 1) ? w2 : w3);
    WtG[idx] = (bf16)w[k * DD + col];
}

// ---------------- K1: MFMA flash attention (no-max streaming softmax) ----------------
// Block: 4 waves, 128 q rows (wave owns 32 = 2 m-tiles). K-tile = 64 keys.
// grid = 32 b * 8 qt = 256
__global__ __launch_bounds__(256, 1) void k_attn(bf16* Xbf,
                                                 const bf16* __restrict__ Pq,
                                                 const bf16* __restrict__ Ptp,
                                                 const float* __restrict__ t) {
    __shared__ bf16 Kt[64 * 136];   // row-major keys (QK^T B-operand)
    __shared__ bf16 Vt[128 * 72];   // d-major, permuted keys (PV B-operand)
    __shared__ float tts[64];
    __shared__ bf16 Pl[4][32 * 72]; // per-wave probs, permuted key' = 4*ln+kt

    const int tid = threadIdx.x;
    const int w = tid >> 6, lane = tid & 63, ln = lane & 15, q3 = lane >> 4;
    const int b = blockIdx.x >> 3, qt = blockIdx.x & 7;
    const long browQ = (long)b * NN + qt * 128 + w * 32;

    // Q fragments (A-operand): rows mt*16+ln, k-chunk c
    bf16x8 Qf[2][4];
#pragma unroll
    for (int mt = 0; mt < 2; ++mt)
#pragma unroll
        for (int c = 0; c < 4; ++c)
            Qf[mt][c] = *(const bf16x8*)&Pq[(browQ + mt * 16 + ln) * DD + c * 32 + q3 * 8];

    f32x4 O[2][8];
    float lsum[2][4];
#pragma unroll
    for (int mt = 0; mt < 2; ++mt) {
#pragma unroll
        for (int nt = 0; nt < 8; ++nt) O[mt][nt] = (f32x4){0.f, 0.f, 0.f, 0.f};
#pragma unroll
        for (int r = 0; r < 4; ++r) lsum[mt][r] = 0.f;
    }

    float4 kreg[4], vreg[4];
    float treg = 0.f;
    auto loadstage = [&](int jt) {
        int j0 = jt * 64;
#pragma unroll
        for (int i = 0; i < 4; ++i) {
            int idx = tid + i * 256;
            kreg[i] = *(const float4*)&Xbf[((long)b * NN + j0 + (idx >> 4)) * 256 + (idx & 15) * 8];
            vreg[i] = *(const float4*)&Ptp[((long)b * DD + (idx >> 3)) * NN + j0 + (idx & 7) * 8];
        }
        treg = (tid < 64) ? t[(long)b * NN + j0 + tid] : 0.f;
    };

    loadstage(0);
    for (int jt = 0; jt < 16; ++jt) {
        __syncthreads();
#pragma unroll
        for (int i = 0; i < 4; ++i) {
            int idx = tid + i * 256;
            *(float4*)&Kt[(idx >> 4) * 136 + (idx & 15) * 8] = kreg[i];
            *(float4*)&Vt[(idx >> 3) * 72 + (idx & 7) * 8] = vreg[i];
        }
        if (tid < 64) tts[tid] = treg;
        __syncthreads();
        if (jt < 15) loadstage(jt + 1);

        float tb[4];
#pragma unroll
        for (int kt = 0; kt < 4; ++kt) tb[kt] = tts[kt * 16 + ln];

        // QK^T -> exp -> Pl (A-layout via permuted b64 writes)
#pragma unroll
        for (int mt = 0; mt < 2; ++mt) {
            float pv[4][4];
#pragma unroll
            for (int kt = 0; kt < 4; ++kt) {
                f32x4 S = (f32x4){0.f, 0.f, 0.f, 0.f};
#pragma unroll
                for (int c = 0; c < 4; ++c)
                    S = MFMA(Qf[mt][c],
                             *(const bf16x8*)&Kt[(kt * 16 + ln) * 136 + c * 32 + q3 * 8], S);
#pragma unroll
                for (int r = 0; r < 4; ++r) {
                    float e = __expf(fminf(S[r] + tb[kt], 80.f));
                    pv[kt][r] = e;
                    lsum[mt][r] += e;
                }
            }
#pragma unroll
            for (int r = 0; r < 4; ++r) {
                bf16x4 pk;
#pragma unroll
                for (int kt = 0; kt < 4; ++kt) pk[kt] = (bf16)pv[kt][r];
                *(bf16x4*)&Pl[w][(mt * 16 + q3 * 4 + r) * 72 + ln * 4] = pk;
            }
        }
        // PV (wave-private Pl round-trip; both sides use permuted key order)
#pragma unroll
        for (int kc = 0; kc < 2; ++kc) {
            bf16x8 Af0 = *(const bf16x8*)&Pl[w][(ln) * 72 + kc * 32 + q3 * 8];
            bf16x8 Af1 = *(const bf16x8*)&Pl[w][(16 + ln) * 72 + kc * 32 + q3 * 8];
#pragma unroll
            for (int nt = 0; nt < 8; ++nt) {
                bf16x8 Vf = *(const bf16x8*)&Vt[(nt * 16 + ln) * 72 + kc * 32 + q3 * 8];
                O[0][nt] = MFMA(Af0, Vf, O[0][nt]);
                O[1][nt] = MFMA(Af1, Vf, O[1][nt]);
            }
        }
    }

    // epilogue: normalize, write attn (bf16) into Xbf cols 128..255
#pragma unroll
    for (int mt = 0; mt < 2; ++mt) {
        float inv[4];
#pragma unroll
        for (int r = 0; r < 4; ++r) {
            float v = lsum[mt][r];
            v += __shfl_xor(v, 1);
            v += __shfl_xor(v, 2);
            v += __shfl_xor(v, 4);
            v += __shfl_xor(v, 8);
            inv[r] = 1.f / v;
        }
#pragma unroll
        for (int nt = 0; nt < 8; ++nt)
#pragma unroll
            for (int r = 0; r < 4; ++r) {
                long row = browQ + mt * 16 + q3 * 4 + r;
                Xbf[row * 256 + 128 + nt * 16 + ln] = (bf16)(O[mt][nt][r] * inv[r]);
            }
    }
}

// ---------------- K2: MFMA gated MLP ----------------
// Y_mat = X(32768x256) @ W_mat(256x128); out = sig(Y2+b2)*P + sig(Y3+b3)*tanh(Y1+b1)
// Block: 4 waves, 128 rows (wave = 32 = 2 m-tiles), all 384 cols. grid = 256.
__global__ __launch_bounds__(256, 1) void k_mlp(const bf16* __restrict__ Xbf,
                                                const bf16* __restrict__ WtG,
                                                const float* __restrict__ P,
                                                const float* __restrict__ b1,
                                                const float* __restrict__ b2,
                                                const float* __restrict__ b3,
                                                float* __restrict__ out) {
    __shared__ bf16 Wsh[384 * 72];  // [wcol][64 k + pad], per 64-k phase
    const int tid = threadIdx.x;
    const int w = tid >> 6, lane = tid & 63, ln = lane & 15, q3 = lane >> 4;
    const long row0 = (long)blockIdx.x * 128 + w * 32;

    bf16x8 Af[2][8];
#pragma unroll
    for (int mt = 0; mt < 2; ++mt)
#pragma unroll
        for (int kc = 0; kc < 8; ++kc)
            Af[mt][kc] = *(const bf16x8*)&Xbf[(row0 + mt * 16 + ln) * 256 + kc * 32 + q3 * 8];

    f32x4 acc[3][2][8];
#pragma unroll
    for (int m = 0; m < 3; ++m)
#pragma unroll
        for (int mt = 0; mt < 2; ++mt)
#pragma unroll
            for (int nt = 0; nt < 8; ++nt) acc[m][mt][nt] = (f32x4){0.f, 0.f, 0.f, 0.f};

    for (int kh = 0; kh < 4; ++kh) {
        __syncthreads();
#pragma unroll
        for (int i = 0; i < 12; ++i) {
            int idx = tid + i * 256;      // 0..3071 ; wcol = idx>>3, c = idx&7
            *(float4*)&Wsh[(idx >> 3) * 72 + (idx & 7) * 8] =
                *(const float4*)&WtG[(idx >> 3) * 256 + kh * 64 + (idx & 7) * 8];
        }
        __syncthreads();
#pragma unroll
        for (int kc2 = 0; kc2 < 2; ++kc2) {
            int kc = kh * 2 + kc2;
#pragma unroll
            for (int mat = 0; mat < 3; ++mat)
#pragma unroll
                for (int nt = 0; nt < 8; ++nt) {
                    bf16x8 Bf = *(const bf16x8*)&Wsh[(mat * 128 + nt * 16 + ln) * 72 +
                                                     kc2 * 32 + q3 * 8];
                    acc[mat][0][nt] = MFMA(Af[0][kc], Bf, acc[mat][0][nt]);
                    acc[mat][1][nt] = MFMA(Af[1][kc], Bf, acc[mat][1][nt]);
                }
        }
    }

#pragma unroll
    for (int mt = 0; mt < 2; ++mt)
#pragma unroll
        for (int nt = 0; nt < 8; ++nt) {
            int col = nt * 16 + ln;
            float bb1 = b1[col], bb2 = b2[col], bb3 = b3[col];
#pragma unroll
            for (int r = 0; r < 4; ++r) {
                long row = row0 + mt * 16 + q3 * 4 + r;
                float y1 = acc[0][mt][nt][r] + bb1;
                float y2 = acc[1][mt][nt][r] + bb2;
                float y3 = acc[2][mt][nt][r] + bb3;
                float p = P[row * DD + col];
                float rg = 1.f / (1.f + __expf(-y2));
                float fg = 1.f / (1.f + __expf(-y3));
                out[row * DD + col] = rg * p + fg * tanhf(y1);
            }
        }
}

extern "C" void kernel_launch(void* const* d_in, const int* in_sizes, int n_in,
                              void* d_out, int out_size, void* d_ws, size_t ws_size,
                              hipStream_t stream) {
    const float* P     = (const float*)d_in[0];
    const float* w_itr = (const float*)d_in[1];
    const float* w1    = (const float*)d_in[2];
    const float* w2    = (const float*)d_in[3];
    const float* w3    = (const float*)d_in[4];
    const float* b1    = (const float*)d_in[5];
    const float* b2    = (const float*)d_in[6];
    const float* b3    = (const float*)d_in[7];
    float* out = (float*)d_out;

    char* wsb = (char*)d_ws;
    bf16* Xbf  = (bf16*)(wsb);                    // 16,777,216 B
    bf16* Pq   = (bf16*)(wsb + 16777216);         //  8,388,608 B
    bf16* Ptp  = (bf16*)(wsb + 25165824);         //  8,388,608 B
    float* tws = (float*)(wsb + 33554432);        //    131,072 B
    bf16* WtG  = (bf16*)(wsb + 33685504);         //    196,608 B  (total ~32.3 MB)

    k_prep<<<dim3(BB * 16), dim3(256), 0, stream>>>(P, w_itr, Xbf, Pq, Ptp, tws);
    k_prepw<<<dim3(384), dim3(256), 0, stream>>>(w1, w2, w3, WtG);
    k_attn<<<dim3(BB * 8), dim3(256), 0, stream>>>(Xbf, Pq, Ptp, tws);
    k_mlp<<<dim3(BB * NN / 128), dim3(256), 0, stream>>>(Xbf, WtG, P, b1, b2, b3, out);
}

// Round 3
// 183.872 us; speedup vs baseline: 5.4641x; 1.0358x over previous
//
#include <hip/hip_runtime.h>
#include <math.h>

#define BB 32
#define NN 1024
#define DD 128

typedef __bf16 bf16;
typedef bf16 bf16x4 __attribute__((ext_vector_type(4)));
typedef bf16 bf16x8 __attribute__((ext_vector_type(8)));
typedef float f32x4 __attribute__((ext_vector_type(4)));
typedef float f32x16 __attribute__((ext_vector_type(16)));

#define MFMA16(a, b, c) __builtin_amdgcn_mfma_f32_16x16x32_bf16(a, b, c, 0, 0, 0)
#define MFMA32(a, b, c) __builtin_amdgcn_mfma_f32_32x32x16_bf16(a, b, c, 0, 0, 0)

__device__ inline bf16x4 swap32(bf16x4 v) {
    union { bf16x4 h; int i[2]; } u, r;
    u.h = v;
    r.i[0] = __shfl_xor(u.i[0], 32, 64);
    r.i[1] = __shfl_xor(u.i[1], 32, 64);
    return r.h;
}

// ---------------- K0: prep ----------------
// Xbf[row][0:128] = bf16(P); Pq = bf16(P*wc); Ptp[b][d][n] = bf16(P[b][n][d]);
// t[b][n] = P_n . wa  (wb is dead: constant over softmax axis j)
__global__ __launch_bounds__(256) void k_prep(const float* __restrict__ P,
                                              const float* __restrict__ w_itr,
                                              bf16* __restrict__ Xbf,
                                              bf16* __restrict__ Pq,
                                              bf16* __restrict__ Ptp,
                                              float* __restrict__ t) {
    __shared__ bf16 Lt[128 * 72];  // transposed tile [d][row]
    int tid = threadIdx.x;
    int b = blockIdx.x >> 4, g = blockIdx.x & 15;
    int n0 = g * 64;
    int row = tid >> 2, q = tid & 3, d0 = q * 32;
    long brow = (long)b * NN + n0 + row;

    const float* src = P + brow * DD + d0;
    float r[32];
#pragma unroll
    for (int i = 0; i < 8; ++i) {
        float4 v = ((const float4*)src)[i];
        r[4 * i + 0] = v.x; r[4 * i + 1] = v.y; r[4 * i + 2] = v.z; r[4 * i + 3] = v.w;
    }
    float s = 0.f;
#pragma unroll
    for (int k = 0; k < 32; ++k) s += r[k] * w_itr[d0 + k];
    s += __shfl_xor(s, 1);
    s += __shfl_xor(s, 2);
    if (q == 0) t[brow] = s;
    const float* wc = w_itr + 2 * DD;
#pragma unroll
    for (int i = 0; i < 4; ++i) {
        bf16x8 xv, qv;
#pragma unroll
        for (int e = 0; e < 8; ++e) {
            float f = r[8 * i + e];
            xv[e] = (bf16)f;
            qv[e] = (bf16)(f * wc[d0 + 8 * i + e]);
        }
        *(bf16x8*)&Xbf[brow * 256 + d0 + 8 * i] = xv;
        *(bf16x8*)&Pq[brow * DD + d0 + 8 * i] = qv;
    }
#pragma unroll
    for (int k = 0; k < 32; ++k) Lt[(d0 + k) * 72 + row] = (bf16)r[k];
    __syncthreads();
#pragma unroll
    for (int i = 0; i < 4; ++i) {
        int idx = tid + i * 256;           // 0..1023
        int d = idx >> 3, c = idx & 7;
        *(float4*)&Ptp[((long)b * DD + d) * NN + n0 + c * 8] =
            *(const float4*)&Lt[d * 72 + c * 8];
    }
}

// ---------------- K0b: weight transpose (LDS-tiled) ----------------
// WtG[mat*128 + col][k] = bf16(w_mat[k][col]); col-major, k stride 1, row stride 256
__global__ __launch_bounds__(256) void k_prepw(const float* __restrict__ w1,
                                               const float* __restrict__ w2,
                                               const float* __restrict__ w3,
                                               bf16* __restrict__ WtG) {
    __shared__ float Lw[32][33];
    int bi = blockIdx.x;                 // 96 = 3 mats * 8 kt * 4 ct
    int mat = bi >> 5, rem = bi & 31;
    int kt = rem >> 2, ct = rem & 3;
    const float* wsrc = (mat == 0) ? w1 : ((mat == 1) ? w2 : w3);
    int tid = threadIdx.x;
#pragma unroll
    for (int p = 0; p < 4; ++p) {
        int idx = tid + p * 256;
        int kr = idx >> 5, c = idx & 31;
        Lw[kr][c] = wsrc[(kt * 32 + kr) * DD + ct * 32 + c];
    }
    __syncthreads();
    int colg = tid >> 3, kq = tid & 7;
    bf16x4 v;
#pragma unroll
    for (int e = 0; e < 4; ++e) v[e] = (bf16)Lw[kq * 4 + e][colg];
    *(bf16x4*)&WtG[(mat * 128 + ct * 32 + colg) * 256 + kt * 32 + kq * 4] = v;
}

// ---------------- K1: MFMA attention, S^T/O^T formulation ----------------
// Block: 256 thr = 4 waves = 2 row-groups (32 q-rows) x 2 key-halves (512 keys).
// S^T = K*Q^T (rows=keys, cols=qrows); P = exp(S+t); O^T = V^T*P.
// grid = 512: b = blk&31 (XCD-affine), qt = blk>>5 (16 tiles of 64 rows).
__global__ __launch_bounds__(256, 2) void k_attn(bf16* __restrict__ Xbf,
                                                 const bf16* __restrict__ Pq,
                                                 const bf16* __restrict__ Ptp,
                                                 const float* __restrict__ t) {
    __shared__ __align__(16) char smem[72704];
    bf16* Kt = (bf16*)smem;                  // [2][64][136]
    bf16* Vt = (bf16*)(smem + 34816);        // [2][128][72]
    float* tsh = (float*)(smem + 71680);     // [2][64]
    float* lbuf = (float*)(smem + 72192);    // [kh][rg][32]
    float* Obuf = (float*)smem;              // [rg][128][36] alias (epilogue)

    const int tid = threadIdx.x;
    const int w = tid >> 6, lane = tid & 63;
    const int col = lane & 31, q = lane >> 5;
    const int kh = w >> 1, rg = w & 1;
    const int b = blockIdx.x & 31, qt = blockIdx.x >> 5;
    const long qbase = (long)b * NN + qt * 64 + rg * 32;

    const bf16* KtH = Kt + kh * (64 * 136);
    const bf16* VtH = Vt + kh * (128 * 72);
    const float* tH = tsh + kh * 64;

    // Q B-fragments (cols=qrows at lane&31), held for whole kernel
    bf16x8 Qb[8];
#pragma unroll
    for (int c = 0; c < 8; ++c)
        Qb[c] = *(const bf16x8*)&Pq[(qbase + col) * DD + c * 16 + q * 8];

    f32x16 O[4];
#pragma unroll
    for (int mt = 0; mt < 4; ++mt)
#pragma unroll
        for (int r = 0; r < 16; ++r) O[mt][r] = 0.f;
    float lsum = 0.f;

    float4 kr[8];
    float tr = 0.f;
    auto loadK = [&](int jt) {
#pragma unroll
        for (int i = 0; i < 8; ++i) {
            int idx = tid + i * 256;            // 0..2047
            int h = idx >> 10, rem = idx & 1023;
            int key = rem >> 4, c16 = rem & 15;
            kr[i] = *(const float4*)&Xbf[((long)b * NN + h * 512 + jt * 64 + key) * 256 + c16 * 8];
        }
        tr = (tid < 128) ? t[(long)b * NN + (tid >> 6) * 512 + jt * 64 + (tid & 63)] : 0.f;
    };

    loadK(0);
    for (int jt = 0; jt < 8; ++jt) {
        __syncthreads();
        // commit prefetched K + t
#pragma unroll
        for (int i = 0; i < 8; ++i) {
            int idx = tid + i * 256;
            int h = idx >> 10, rem = idx & 1023;
            int key = rem >> 4, c16 = rem & 15;
            *(float4*)&Kt[h * (64 * 136) + key * 136 + c16 * 8] = kr[i];
        }
        if (tid < 128) tsh[tid] = tr;
        // stream V
        float4 vr[8];
#pragma unroll
        for (int i = 0; i < 8; ++i) {
            int idx = tid + i * 256;
            int h = idx >> 10, rem = idx & 1023;
            int d = rem >> 3, c8 = rem & 7;
            vr[i] = *(const float4*)&Ptp[((long)b * DD + d) * NN + h * 512 + jt * 64 + c8 * 8];
        }
#pragma unroll
        for (int i = 0; i < 8; ++i) {
            int idx = tid + i * 256;
            int h = idx >> 10, rem = idx & 1023;
            int d = rem >> 3, c8 = rem & 7;
            *(float4*)&Vt[h * (128 * 72) + d * 72 + c8 * 8] = vr[i];
        }
        __syncthreads();
        if (jt < 7) loadK(jt + 1);

#pragma unroll
        for (int kt = 0; kt < 2; ++kt) {
            f32x16 S;
#pragma unroll
            for (int r = 0; r < 16; ++r) S[r] = 0.f;
#pragma unroll
            for (int c = 0; c < 8; ++c)
                S = MFMA32(*(const bf16x8*)&KtH[(kt * 32 + col) * 136 + c * 16 + q * 8],
                           Qb[c], S);
            // bias rows (keys) + exp; lsum is pure per-lane
            float tqs[16];
#pragma unroll
            for (int i = 0; i < 4; ++i) {
                float4 tv = *(const float4*)&tH[kt * 32 + 8 * i + 4 * q];
                tqs[4 * i + 0] = tv.x; tqs[4 * i + 1] = tv.y;
                tqs[4 * i + 2] = tv.z; tqs[4 * i + 3] = tv.w;
            }
            float pv[16];
#pragma unroll
            for (int r = 0; r < 16; ++r) {
                float e = __expf(fminf(S[r] + tqs[r], 80.f));
                pv[r] = e;
                lsum += e;
            }
            // pack quads, half-swap into B-fragments (k = 8q + j)
            bf16x4 Qd[4];
#pragma unroll
            for (int i = 0; i < 4; ++i)
#pragma unroll
                for (int e = 0; e < 4; ++e) Qd[i][e] = (bf16)pv[4 * i + e];
            bf16x4 sA = q ? Qd[0] : Qd[1];
            bf16x4 rA = swap32(sA);
            bf16x4 sB = q ? Qd[2] : Qd[3];
            bf16x4 rB = swap32(sB);
            bf16x4 lo0 = q ? rA : Qd[0], hi0 = q ? Qd[1] : rA;
            bf16x4 lo1 = q ? rB : Qd[2], hi1 = q ? Qd[3] : rB;
            bf16x8 f0, f1;
#pragma unroll
            for (int e = 0; e < 4; ++e) {
                f0[e] = lo0[e]; f0[4 + e] = hi0[e];
                f1[e] = lo1[e]; f1[4 + e] = hi1[e];
            }
            // O^T += V^T * P  (chunks 2kt, 2kt+1)
#pragma unroll
            for (int mt = 0; mt < 4; ++mt) {
                O[mt] = MFMA32(*(const bf16x8*)&VtH[(mt * 32 + col) * 72 + kt * 32 + q * 8],
                               f0, O[mt]);
                O[mt] = MFMA32(*(const bf16x8*)&VtH[(mt * 32 + col) * 72 + kt * 32 + 16 + q * 8],
                               f1, O[mt]);
            }
        }
    }

    // ---- merge key-halves, normalize, coalesced bf16 write ----
    float l2 = lsum + __shfl_xor(lsum, 32, 64);
    if (q == 0) lbuf[(kh * 2 + rg) * 32 + col] = l2;
    __syncthreads();   // all compute done; Kt/Vt dead -> Obuf alias safe
    if (kh == 1) {
#pragma unroll
        for (int mt = 0; mt < 4; ++mt)
#pragma unroll
            for (int r = 0; r < 16; ++r) {
                int d = mt * 32 + (r & 3) + 8 * (r >> 2) + 4 * q;
                Obuf[(rg * 128 + d) * 36 + col] = O[mt][r];
            }
    }
    __syncthreads();
    if (kh == 0) {
        float linv = 1.f / (lbuf[(0 * 2 + rg) * 32 + col] + lbuf[(1 * 2 + rg) * 32 + col]);
#pragma unroll
        for (int mt = 0; mt < 4; ++mt)
#pragma unroll
            for (int r = 0; r < 16; ++r) {
                int d = mt * 32 + (r & 3) + 8 * (r >> 2) + 4 * q;
                int ix = (rg * 128 + d) * 36 + col;
                Obuf[ix] = (O[mt][r] + Obuf[ix]) * linv;
            }
    }
    __syncthreads();
    {   // transpose-write: row-major bf16 into Xbf cols 128..255
        int colg = tid & 31, rg2 = (tid >> 5) & 1, w4 = tid >> 6;
        long grow = (long)b * NN + qt * 64 + rg2 * 32 + colg;
#pragma unroll
        for (int p = 0; p < 4; ++p) {
            bf16x8 v8;
#pragma unroll
            for (int e = 0; e < 8; ++e)
                v8[e] = (bf16)Obuf[(rg2 * 128 + w4 * 32 + p * 8 + e) * 36 + colg];
            *(bf16x8*)&Xbf[grow * 256 + 128 + w4 * 32 + p * 8] = v8;
        }
    }
}

// ---------------- K2: MFMA gated MLP (no LDS, W-frags from L1/L2) ----------------
// Block: 4 waves = 2 row-groups x 2 col-halves; 64 rows, grid 512.
// Sequential mats with stashed gates: z=tanh(Y1+b1), r=sig(Y2+b2), f=sig(Y3+b3).
__global__ __launch_bounds__(256, 2) void k_mlp(const bf16* __restrict__ Xbf,
                                                const bf16* __restrict__ WtG,
                                                const float* __restrict__ P,
                                                const float* __restrict__ b1,
                                                const float* __restrict__ b2,
                                                const float* __restrict__ b3,
                                                float* __restrict__ out) {
    const int tid = threadIdx.x;
    const int w = tid >> 6, lane = tid & 63, ln = lane & 15, q3 = lane >> 4;
    const int rg = w & 1, ch = w >> 1;
    const long row0 = (long)blockIdx.x * 64 + rg * 32;

    bf16x8 Af[2][8];
#pragma unroll
    for (int mt = 0; mt < 2; ++mt)
#pragma unroll
        for (int kc = 0; kc < 8; ++kc)
            Af[mt][kc] = *(const bf16x8*)&Xbf[(row0 + mt * 16 + ln) * 256 + kc * 32 + q3 * 8];

    f32x4 stz[2][4], str[2][4];
#pragma unroll
    for (int mat = 0; mat < 3; ++mat) {
        f32x4 acc[2][4];
#pragma unroll
        for (int mt = 0; mt < 2; ++mt)
#pragma unroll
            for (int nt = 0; nt < 4; ++nt) acc[mt][nt] = (f32x4){0.f, 0.f, 0.f, 0.f};
#pragma unroll
        for (int kc = 0; kc < 8; ++kc)
#pragma unroll
            for (int nt = 0; nt < 4; ++nt) {
                bf16x8 Bf = *(const bf16x8*)&WtG[(mat * 128 + ch * 64 + nt * 16 + ln) * 256 +
                                                 kc * 32 + q3 * 8];
                acc[0][nt] = MFMA16(Af[0][kc], Bf, acc[0][nt]);
                acc[1][nt] = MFMA16(Af[1][kc], Bf, acc[1][nt]);
            }
        const float* bp = (mat == 0) ? b1 : ((mat == 1) ? b2 : b3);
#pragma unroll
        for (int mt = 0; mt < 2; ++mt)
#pragma unroll
            for (int nt = 0; nt < 4; ++nt) {
                int colc = ch * 64 + nt * 16 + ln;
                float bb = bp[colc];
#pragma unroll
                for (int r = 0; r < 4; ++r) {
                    float y = acc[mt][nt][r] + bb;
                    if (mat == 0) stz[mt][nt][r] = tanhf(y);
                    else if (mat == 1) str[mt][nt][r] = 1.f / (1.f + __expf(-y));
                    else {
                        float fg = 1.f / (1.f + __expf(-y));
                        long row = row0 + mt * 16 + q3 * 4 + r;
                        float p = P[row * DD + colc];
                        out[row * DD + colc] = str[mt][nt][r] * p + fg * stz[mt][nt][r];
                    }
                }
            }
    }
}

extern "C" void kernel_launch(void* const* d_in, const int* in_sizes, int n_in,
                              void* d_out, int out_size, void* d_ws, size_t ws_size,
                              hipStream_t stream) {
    const float* P     = (const float*)d_in[0];
    const float* w_itr = (const float*)d_in[1];
    const float* w1    = (const float*)d_in[2];
    const float* w2    = (const float*)d_in[3];
    const float* w3    = (const float*)d_in[4];
    const float* b1    = (const float*)d_in[5];
    const float* b2    = (const float*)d_in[6];
    const float* b3    = (const float*)d_in[7];
    float* out = (float*)d_out;

    char* wsb = (char*)d_ws;
    bf16* Xbf  = (bf16*)(wsb);                    // 16,777,216 B
    bf16* Pq   = (bf16*)(wsb + 16777216);         //  8,388,608 B
    bf16* Ptp  = (bf16*)(wsb + 25165824);         //  8,388,608 B
    float* tws = (float*)(wsb + 33554432);        //    131,072 B
    bf16* WtG  = (bf16*)(wsb + 33685504);         //    196,608 B

    k_prep<<<dim3(BB * 16), dim3(256), 0, stream>>>(P, w_itr, Xbf, Pq, Ptp, tws);
    k_prepw<<<dim3(96), dim3(256), 0, stream>>>(w1, w2, w3, WtG);
    k_attn<<<dim3(512), dim3(256), 0, stream>>>(Xbf, Pq, Ptp, tws);
    k_mlp<<<dim3(512), dim3(256), 0, stream>>>(Xbf, WtG, P, b1, b2, b3, out);
}